// Round 5
// baseline (649.643 us; speedup 1.0000x reference)
//
#include <hip/hip_runtime.h>
#include <math.h>

#define TT 4096
#define DM 512
#define NH 8
#define HD 64
#define WN (DM * DM)   // 262144 elements per weight matrix

typedef float f32x4 __attribute__((ext_vector_type(4)));
typedef short short8 __attribute__((ext_vector_type(8)));

static __device__ __forceinline__ float bf2f(unsigned short h) {
    unsigned int u = ((unsigned int)h) << 16;
    return __builtin_bit_cast(float, u);
}
// truncation split: hi = trunc_bf16(x), lo = trunc_bf16(x - hi). Net rel err ~2^-15.
static __device__ __forceinline__ void splitbf(float x, unsigned short& hi, unsigned short& lo) {
    unsigned int u = __builtin_bit_cast(unsigned int, x);
    hi = (unsigned short)(u >> 16);
    float r = x - bf2f(hi);
    lo = (unsigned short)(__builtin_bit_cast(unsigned int, r) >> 16);
}
// Q-row permutation: LDS row rho holds global q-row qperm(rho). Maps MFMA C-rows
// (lg*4+r) onto PV B-frag k-slots (lg*8+j) so P stays in registers.
static __device__ __forceinline__ int qperm(int r) {
    return ((r >> 5) << 5) | (((r >> 2) & 3) << 3) | (((r >> 4) & 1) << 2) | (r & 3);
}

// ---------------------------------------------------------------------------
// Pre-split the three weight matrices into bf16 hi/lo. grid (128, 3), 256 thr.
// ---------------------------------------------------------------------------
__global__ __launch_bounds__(256) void wsplit(
    const float* __restrict__ Wq, const float* __restrict__ Wk, const float* __restrict__ Wv,
    unsigned short* __restrict__ Whi, unsigned short* __restrict__ Wlo)
{
    const int z = blockIdx.y;
    const float* __restrict__ src = (z == 0) ? Wq : (z == 1) ? Wk : Wv;
    const int i = (blockIdx.x * 256 + threadIdx.x) * 8;
    float4 a = *(const float4*)&src[i];
    float4 b = *(const float4*)&src[i + 4];
    float v[8] = {a.x, a.y, a.z, a.w, b.x, b.y, b.z, b.w};
    unsigned short hb[8], lb[8];
    #pragma unroll
    for (int k = 0; k < 8; ++k) splitbf(v[k], hb[k], lb[k]);
    uint4 hv, lv;
    hv.x = (unsigned int)hb[0] | ((unsigned int)hb[1] << 16);
    hv.y = (unsigned int)hb[2] | ((unsigned int)hb[3] << 16);
    hv.z = (unsigned int)hb[4] | ((unsigned int)hb[5] << 16);
    hv.w = (unsigned int)hb[6] | ((unsigned int)hb[7] << 16);
    lv.x = (unsigned int)lb[0] | ((unsigned int)lb[1] << 16);
    lv.y = (unsigned int)lb[2] | ((unsigned int)lb[3] << 16);
    lv.z = (unsigned int)lb[4] | ((unsigned int)lb[5] << 16);
    lv.w = (unsigned int)lb[6] | ((unsigned int)lb[7] << 16);
    *(uint4*)&Whi[(size_t)z * WN + i] = hv;
    *(uint4*)&Wlo[(size_t)z * WN + i] = lv;
}

// ---------------------------------------------------------------------------
// Projection via 3-term split-bf16 MFMA. Y = X @ W^T + bias.
// grid (M/128, 512/64, 3), 256 thr (4 waves), BM=128 BN=64 BK=64.
// ---------------------------------------------------------------------------
__global__ __launch_bounds__(256, 2) void proj_mfma(
    const float* __restrict__ X,
    const unsigned short* __restrict__ Whi, const unsigned short* __restrict__ Wlo,
    const float* __restrict__ bq, const float* __restrict__ bk, const float* __restrict__ bv,
    unsigned short* __restrict__ Qhi, unsigned short* __restrict__ Qlo,
    unsigned short* __restrict__ Khi, unsigned short* __restrict__ Klo,
    unsigned short* __restrict__ Vthi, unsigned short* __restrict__ Vtlo)
{
    const int z = blockIdx.z;
    const int m0 = blockIdx.x * 128;
    const int n0 = blockIdx.y * 64;
    const int tid = threadIdx.x;
    const int wid = tid >> 6, lane = tid & 63;
    const int lg = lane >> 4, lr = lane & 15;

    __shared__ __attribute__((aligned(16))) unsigned short smem[384 * 72];
    auto Xh  = (unsigned short(*)[72])(smem);
    auto Xl  = (unsigned short(*)[72])(smem + 128 * 72);
    auto Wh2 = (unsigned short(*)[72])(smem + 256 * 72);
    auto Wl2 = (unsigned short(*)[72])(smem + 320 * 72);

    const unsigned short* __restrict__ Wh = Whi + (size_t)z * WN;
    const unsigned short* __restrict__ Wl = Wlo + (size_t)z * WN;

    f32x4 acc[2][4];
    #pragma unroll
    for (int rt = 0; rt < 2; ++rt)
        #pragma unroll
        for (int nt = 0; nt < 4; ++nt) acc[rt][nt] = (f32x4){0.f, 0.f, 0.f, 0.f};

    const int xr = tid >> 1;
    const int xc = (tid & 1) * 32;

    for (int k0 = 0; k0 < DM; k0 += 64) {
        #pragma unroll
        for (int w = 0; w < 4; ++w) {
            float4 fa = *(const float4*)&X[(size_t)(m0 + xr) * DM + k0 + xc + w * 8];
            float4 fb = *(const float4*)&X[(size_t)(m0 + xr) * DM + k0 + xc + w * 8 + 4];
            float v[8] = {fa.x, fa.y, fa.z, fa.w, fb.x, fb.y, fb.z, fb.w};
            unsigned short hb[8], lb[8];
            #pragma unroll
            for (int k = 0; k < 8; ++k) splitbf(v[k], hb[k], lb[k]);
            uint4 hv, lv;
            hv.x = (unsigned int)hb[0] | ((unsigned int)hb[1] << 16);
            hv.y = (unsigned int)hb[2] | ((unsigned int)hb[3] << 16);
            hv.z = (unsigned int)hb[4] | ((unsigned int)hb[5] << 16);
            hv.w = (unsigned int)hb[6] | ((unsigned int)hb[7] << 16);
            lv.x = (unsigned int)lb[0] | ((unsigned int)lb[1] << 16);
            lv.y = (unsigned int)lb[2] | ((unsigned int)lb[3] << 16);
            lv.z = (unsigned int)lb[4] | ((unsigned int)lb[5] << 16);
            lv.w = (unsigned int)lb[6] | ((unsigned int)lb[7] << 16);
            *(uint4*)&Xh[xr][xc + w * 8] = hv;
            *(uint4*)&Xl[xr][xc + w * 8] = lv;
        }
        #pragma unroll
        for (int it = 0; it < 2; ++it) {
            int i2 = it * 256 + tid;
            int fr = i2 >> 3, ch = i2 & 7;
            *(int4*)&Wh2[fr][ch * 8] = *(const int4*)&Wh[(size_t)(n0 + fr) * DM + k0 + ch * 8];
            *(int4*)&Wl2[fr][ch * 8] = *(const int4*)&Wl[(size_t)(n0 + fr) * DM + k0 + ch * 8];
        }
        __syncthreads();

        __builtin_amdgcn_s_setprio(1);
        #pragma unroll
        for (int kc = 0; kc < 2; ++kc) {
            short8 xa[2][2];
            #pragma unroll
            for (int rt = 0; rt < 2; ++rt) {
                xa[rt][0] = __builtin_bit_cast(short8, *(const int4*)&Xh[wid * 32 + rt * 16 + lr][kc * 32 + lg * 8]);
                xa[rt][1] = __builtin_bit_cast(short8, *(const int4*)&Xl[wid * 32 + rt * 16 + lr][kc * 32 + lg * 8]);
            }
            #pragma unroll
            for (int nt = 0; nt < 4; ++nt) {
                short8 wh = __builtin_bit_cast(short8, *(const int4*)&Wh2[nt * 16 + lr][kc * 32 + lg * 8]);
                short8 wl = __builtin_bit_cast(short8, *(const int4*)&Wl2[nt * 16 + lr][kc * 32 + lg * 8]);
                #pragma unroll
                for (int rt = 0; rt < 2; ++rt) {
                    acc[rt][nt] = __builtin_amdgcn_mfma_f32_16x16x32_bf16(xa[rt][0], wh, acc[rt][nt], 0, 0, 0);
                    acc[rt][nt] = __builtin_amdgcn_mfma_f32_16x16x32_bf16(xa[rt][1], wh, acc[rt][nt], 0, 0, 0);
                    acc[rt][nt] = __builtin_amdgcn_mfma_f32_16x16x32_bf16(xa[rt][0], wl, acc[rt][nt], 0, 0, 0);
                }
            }
        }
        __builtin_amdgcn_s_setprio(0);
        __syncthreads();
    }

    if (z < 2) {
        const float* __restrict__ bias = (z == 0) ? bq : bk;
        unsigned short* __restrict__ Hi = (z == 0) ? Qhi : Khi;
        unsigned short* __restrict__ Lo = (z == 0) ? Qlo : Klo;
        const float sc = (z == 0) ? 0.125f : 1.0f;
        #pragma unroll
        for (int nt = 0; nt < 4; ++nt) {
            int n = n0 + nt * 16 + lr;
            float bv_ = bias[n];
            #pragma unroll
            for (int rt = 0; rt < 2; ++rt)
                #pragma unroll
                for (int r = 0; r < 4; ++r) {
                    int m = m0 + wid * 32 + rt * 16 + lg * 4 + r;
                    float y = (acc[rt][nt][r] + bv_) * sc;
                    unsigned short hb, lb;
                    splitbf(y, hb, lb);
                    Hi[(size_t)m * DM + n] = hb;
                    Lo[(size_t)m * DM + n] = lb;
                }
        }
    } else {
        unsigned int* Tk = (unsigned int*)smem;
        #pragma unroll
        for (int nt = 0; nt < 4; ++nt) {
            int d = nt * 16 + lr;
            float bv_ = bv[n0 + d];
            #pragma unroll
            for (int rt = 0; rt < 2; ++rt)
                #pragma unroll
                for (int r = 0; r < 4; ++r) {
                    int t = wid * 32 + rt * 16 + lg * 4 + r;
                    float y = acc[rt][nt][r] + bv_;
                    unsigned short hb, lb;
                    splitbf(y, hb, lb);
                    Tk[d * 132 + t] = (unsigned int)hb | ((unsigned int)lb << 16);
                }
        }
        __syncthreads();
        const int dl = tid >> 2, tq = tid & 3;
        const int bb = m0 >> 12, t0 = m0 & (TT - 1), h = n0 >> 6;
        size_t obase = ((size_t)((bb * NH + h) * HD + dl)) * TT + t0 + tq * 32;
        unsigned int hw[16], lw[16];
        #pragma unroll
        for (int k = 0; k < 16; ++k) {
            unsigned int u0 = Tk[dl * 132 + tq * 32 + 2 * k];
            unsigned int u1 = Tk[dl * 132 + tq * 32 + 2 * k + 1];
            hw[k] = (u0 & 0xFFFFu) | (u1 << 16);
            lw[k] = (u0 >> 16) | (u1 & 0xFFFF0000u);
        }
        #pragma unroll
        for (int j = 0; j < 4; ++j) {
            uint4 hv = {hw[4 * j], hw[4 * j + 1], hw[4 * j + 2], hw[4 * j + 3]};
            uint4 lv = {lw[4 * j], lw[4 * j + 1], lw[4 * j + 2], lw[4 * j + 3]};
            *(uint4*)&Vthi[obase + j * 8] = hv;
            *(uint4*)&Vtlo[obase + j * 8] = lv;
        }
    }
}

// ---------------------------------------------------------------------------
// Flash attention, operand-swapped: S^T = mfma(Q,K) (row=q~, col=krow),
// out^T = mfma(V^T,P) (row=d, col=krow). Q rows staged under qperm so the
// P fragments are lane-local register packs (no P LDS, no cross-lane P moves).
// 64 krows/block (16 per wave) -> grid 1024 = 4 blocks/CU, no spill.
// ---------------------------------------------------------------------------
__global__ __launch_bounds__(256, 4) void attn_mfma(
    const unsigned short* __restrict__ Qhi, const unsigned short* __restrict__ Qlo,
    const unsigned short* __restrict__ Khi, const unsigned short* __restrict__ Klo,
    const unsigned short* __restrict__ Vthi, const unsigned short* __restrict__ Vtlo,
    float* __restrict__ Out)
{
    const int b = blockIdx.z, h = blockIdx.y;
    const int r0 = blockIdx.x * 64;
    const int tid = threadIdx.x;
    const int wid = tid >> 6, lane = tid & 63;
    const int lg = lane >> 4, lr = lane & 15;
    const int wr0 = r0 + wid * 16;

    __shared__ __attribute__((aligned(16))) unsigned short Qs[128][72]; // permuted q rows: hi 0-63, lo 64-127
    __shared__ __attribute__((aligned(16))) unsigned short Vs[128][72]; // V^T rows d: hi 0-63, lo 64-127

    // K fragments (B-operand: col=krow=lr, k=d) resident in registers
    short8 kf[2][2];
    #pragma unroll
    for (int kc = 0; kc < 2; ++kc) {
        int row = wr0 + lr;
        size_t g = ((size_t)(b * TT + row)) * DM + h * HD + kc * 32 + lg * 8;
        kf[kc][0] = __builtin_bit_cast(short8, *(const int4*)&Khi[g]);
        kf[kc][1] = __builtin_bit_cast(short8, *(const int4*)&Klo[g]);
    }

    // prologue: prefetch tile 0 into registers (Q rows permuted)
    int4 qreg[4], vreg[4];
    #pragma unroll
    for (int it = 0; it < 4; ++it) {
        int gi = it * 256 + tid, fr = gi >> 3, ch = gi & 7;
        int qrow = qperm(fr & 63);
        const unsigned short* qsrc = (fr < 64) ? Qhi : Qlo;
        qreg[it] = *(const int4*)&qsrc[((size_t)(b * TT + qrow)) * DM + h * HD + ch * 8];
        const unsigned short* vsrc = (fr < 64) ? Vthi : Vtlo;
        vreg[it] = *(const int4*)&vsrc[((size_t)((b * NH + h) * HD + (fr & 63))) * TT + ch * 8];
    }

    float m_s = -INFINITY, l_s = 0.f;
    f32x4 oacc[4];
    #pragma unroll
    for (int dt = 0; dt < 4; ++dt) oacc[dt] = (f32x4){0.f, 0.f, 0.f, 0.f};

    for (int c0 = 0; c0 < TT; c0 += 64) {
        #pragma unroll
        for (int it = 0; it < 4; ++it) {
            int gi = it * 256 + tid, fr = gi >> 3, ch = gi & 7;
            *(int4*)&Qs[fr][ch * 8] = qreg[it];
            *(int4*)&Vs[fr][ch * 8] = vreg[it];
        }
        __syncthreads();

        // prefetch next tile
        int cn = c0 + 64; if (cn >= TT) cn = 0;
        #pragma unroll
        for (int it = 0; it < 4; ++it) {
            int gi = it * 256 + tid, fr = gi >> 3, ch = gi & 7;
            int qrow = cn + qperm(fr & 63);
            const unsigned short* qsrc = (fr < 64) ? Qhi : Qlo;
            qreg[it] = *(const int4*)&qsrc[((size_t)(b * TT + qrow)) * DM + h * HD + ch * 8];
            const unsigned short* vsrc = (fr < 64) ? Vthi : Vtlo;
            vreg[it] = *(const int4*)&vsrc[((size_t)((b * NH + h) * HD + (fr & 63))) * TT + cn + ch * 8];
        }

        // S^T = Q @ K^T (3-term split): sacc[qt] row=q~tile-row, col=krow
        f32x4 sacc[4];
        #pragma unroll
        for (int qt = 0; qt < 4; ++qt) sacc[qt] = (f32x4){0.f, 0.f, 0.f, 0.f};
        __builtin_amdgcn_s_setprio(1);
        #pragma unroll
        for (int kc = 0; kc < 2; ++kc) {
            #pragma unroll
            for (int qt = 0; qt < 4; ++qt) {
                short8 qh = __builtin_bit_cast(short8, *(const int4*)&Qs[qt * 16 + lr][kc * 32 + lg * 8]);
                short8 ql = __builtin_bit_cast(short8, *(const int4*)&Qs[64 + qt * 16 + lr][kc * 32 + lg * 8]);
                sacc[qt] = __builtin_amdgcn_mfma_f32_16x16x32_bf16(qh, kf[kc][0], sacc[qt], 0, 0, 0);
                sacc[qt] = __builtin_amdgcn_mfma_f32_16x16x32_bf16(ql, kf[kc][0], sacc[qt], 0, 0, 0);
                sacc[qt] = __builtin_amdgcn_mfma_f32_16x16x32_bf16(qh, kf[kc][1], sacc[qt], 0, 0, 0);
            }
        }
        __builtin_amdgcn_s_setprio(0);

        // online softmax (per-lane: krow = wr0+lr across lg groups) + pack P
        unsigned int hp[4][2], lp[4][2];
        {
            float mx = -INFINITY;
            #pragma unroll
            for (int qt = 0; qt < 4; ++qt)
                #pragma unroll
                for (int r = 0; r < 4; ++r) mx = fmaxf(mx, sacc[qt][r]);
            mx = fmaxf(mx, __shfl_xor(mx, 16));
            mx = fmaxf(mx, __shfl_xor(mx, 32));
            float nm = fmaxf(m_s, mx);
            float al = __expf(m_s - nm);
            float sum = 0.f;
            #pragma unroll
            for (int qt = 0; qt < 4; ++qt)
                #pragma unroll
                for (int r = 0; r < 4; ++r) {
                    float p = __expf(sacc[qt][r] - nm);
                    sacc[qt][r] = p;
                    sum += p;
                }
            sum += __shfl_xor(sum, 16);
            sum += __shfl_xor(sum, 32);
            m_s = nm;
            l_s = l_s * al + sum;
            // pack: r-pairs -> u32 of 2 bf16 (these ARE the PV B-frag words)
            #pragma unroll
            for (int qt = 0; qt < 4; ++qt)
                #pragma unroll
                for (int pp = 0; pp < 2; ++pp) {
                    float p0 = sacc[qt][2 * pp];
                    float p1 = sacc[qt][2 * pp + 1];
                    unsigned int u0 = __builtin_bit_cast(unsigned int, p0);
                    unsigned int u1 = __builtin_bit_cast(unsigned int, p1);
                    unsigned int h0 = u0 >> 16, h1 = u1 & 0xFFFF0000u;
                    hp[qt][pp] = h0 | h1;
                    float r0f = p0 - bf2f((unsigned short)h0);
                    float r1f = p1 - bf2f((unsigned short)(u1 >> 16));
                    lp[qt][pp] = (__builtin_bit_cast(unsigned int, r0f) >> 16)
                               | (__builtin_bit_cast(unsigned int, r1f) & 0xFFFF0000u);
                }
            // rescale accumulated output
            #pragma unroll
            for (int dt = 0; dt < 4; ++dt)
                #pragma unroll
                for (int r = 0; r < 4; ++r) oacc[dt][r] *= al;
        }

        // out^T += V^T @ P (3-term split)
        __builtin_amdgcn_s_setprio(1);
        #pragma unroll
        for (int c = 0; c < 2; ++c) {
            int4 ph4 = {(int)hp[2 * c][0], (int)hp[2 * c][1],
                        (int)hp[2 * c + 1][0], (int)hp[2 * c + 1][1]};
            int4 pl4 = {(int)lp[2 * c][0], (int)lp[2 * c][1],
                        (int)lp[2 * c + 1][0], (int)lp[2 * c + 1][1]};
            short8 pf  = __builtin_bit_cast(short8, ph4);
            short8 plf = __builtin_bit_cast(short8, pl4);
            #pragma unroll
            for (int dt = 0; dt < 4; ++dt) {
                short8 vh = __builtin_bit_cast(short8, *(const int4*)&Vs[dt * 16 + lr][c * 32 + lg * 8]);
                short8 vl = __builtin_bit_cast(short8, *(const int4*)&Vs[64 + dt * 16 + lr][c * 32 + lg * 8]);
                oacc[dt] = __builtin_amdgcn_mfma_f32_16x16x32_bf16(vh, pf,  oacc[dt], 0, 0, 0);
                oacc[dt] = __builtin_amdgcn_mfma_f32_16x16x32_bf16(vl, pf,  oacc[dt], 0, 0, 0);
                oacc[dt] = __builtin_amdgcn_mfma_f32_16x16x32_bf16(vh, plf, oacc[dt], 0, 0, 0);
            }
        }
        __builtin_amdgcn_s_setprio(0);
        __syncthreads();
    }

    // epilogue: out[krow][d] = oacc / l  (all lane-local)
    {
        float inv = __builtin_amdgcn_rcpf(l_s);
        int row = wr0 + lr;
        #pragma unroll
        for (int dt = 0; dt < 4; ++dt)
            #pragma unroll
            for (int r = 0; r < 4; ++r)
                Out[((size_t)(b * TT + row)) * DM + h * HD + dt * 16 + lg * 4 + r] =
                    oacc[dt][r] * inv;
    }
}

// ---------------------------------------------------------------------------
extern "C" void kernel_launch(void* const* d_in, const int* in_sizes, int n_in,
                              void* d_out, int out_size, void* d_ws, size_t ws_size,
                              hipStream_t stream)
{
    const float* x  = (const float*)d_in[0];
    const float* Wk = (const float*)d_in[1];
    const float* bk = (const float*)d_in[2];
    const float* Wq = (const float*)d_in[3];
    const float* bq = (const float*)d_in[4];
    const float* Wv = (const float*)d_in[5];
    const float* bv = (const float*)d_in[6];
    float* out = (float*)d_out;

    const size_t SZ = (size_t)2 * TT * DM;
    unsigned short* Qhi  = (unsigned short*)d_ws;
    unsigned short* Qlo  = Qhi + SZ;
    unsigned short* Khi  = Qlo + SZ;
    unsigned short* Klo  = Khi + SZ;
    unsigned short* Vthi = Klo + SZ;
    unsigned short* Vtlo = Vthi + SZ;
    unsigned short* Whi  = Vtlo + SZ;
    unsigned short* Wlo  = Whi + (size_t)3 * WN;

    wsplit<<<dim3(WN / 2048, 3), dim3(256), 0, stream>>>(Wq, Wk, Wv, Whi, Wlo);

    dim3 pgrid(2 * TT / 128, DM / 64, 3);
    proj_mfma<<<pgrid, dim3(256), 0, stream>>>(x, Whi, Wlo, bq, bk, bv,
                                               Qhi, Qlo, Khi, Klo, Vthi, Vtlo);

    dim3 agrid(TT / 64, NH, 2);
    attn_mfma<<<agrid, dim3(256), 0, stream>>>(Qhi, Qlo, Khi, Klo, Vthi, Vtlo, out);
}

// Round 6
// 287.921 us; speedup vs baseline: 2.2563x; 2.2563x over previous
//
#include <hip/hip_runtime.h>
#include <math.h>

#define TT 4096
#define DM 512
#define NH 8
#define HD 64
#define WN (DM * DM)   // 262144 elements per weight matrix

typedef float f32x4 __attribute__((ext_vector_type(4)));
typedef short short8 __attribute__((ext_vector_type(8)));

#define GLD16(gp, lp) __builtin_amdgcn_global_load_lds( \
    (const __attribute__((address_space(1))) void*)(gp), \
    (__attribute__((address_space(3))) void*)(lp), 16, 0, 0)

static __device__ __forceinline__ float bf2f(unsigned short h) {
    unsigned int u = ((unsigned int)h) << 16;
    return __builtin_bit_cast(float, u);
}
// truncation split: hi = trunc_bf16(x), lo = trunc_bf16(x - hi). Net rel err ~2^-15.
static __device__ __forceinline__ void splitbf(float x, unsigned short& hi, unsigned short& lo) {
    unsigned int u = __builtin_bit_cast(unsigned int, x);
    hi = (unsigned short)(u >> 16);
    float r = x - bf2f(hi);
    lo = (unsigned short)(__builtin_bit_cast(unsigned int, r) >> 16);
}
// Q-row permutation: LDS row rho holds global q-row qperm(rho). Maps MFMA C-rows
// (lg*4+r) onto PV B-frag k-slots (lg*8+j) so P stays in registers.
static __device__ __forceinline__ int qperm(int r) {
    return ((r >> 5) << 5) | (((r >> 2) & 3) << 3) | (((r >> 4) & 1) << 2) | (r & 3);
}

// ---------------------------------------------------------------------------
// Pre-split the three weight matrices into bf16 hi/lo. grid (128, 3), 256 thr.
// ---------------------------------------------------------------------------
__global__ __launch_bounds__(256) void wsplit(
    const float* __restrict__ Wq, const float* __restrict__ Wk, const float* __restrict__ Wv,
    unsigned short* __restrict__ Whi, unsigned short* __restrict__ Wlo)
{
    const int z = blockIdx.y;
    const float* __restrict__ src = (z == 0) ? Wq : (z == 1) ? Wk : Wv;
    const int i = (blockIdx.x * 256 + threadIdx.x) * 8;
    float4 a = *(const float4*)&src[i];
    float4 b = *(const float4*)&src[i + 4];
    float v[8] = {a.x, a.y, a.z, a.w, b.x, b.y, b.z, b.w};
    unsigned short hb[8], lb[8];
    #pragma unroll
    for (int k = 0; k < 8; ++k) splitbf(v[k], hb[k], lb[k]);
    uint4 hv, lv;
    hv.x = (unsigned int)hb[0] | ((unsigned int)hb[1] << 16);
    hv.y = (unsigned int)hb[2] | ((unsigned int)hb[3] << 16);
    hv.z = (unsigned int)hb[4] | ((unsigned int)hb[5] << 16);
    hv.w = (unsigned int)hb[6] | ((unsigned int)hb[7] << 16);
    lv.x = (unsigned int)lb[0] | ((unsigned int)lb[1] << 16);
    lv.y = (unsigned int)lb[2] | ((unsigned int)lb[3] << 16);
    lv.z = (unsigned int)lb[4] | ((unsigned int)lb[5] << 16);
    lv.w = (unsigned int)lb[6] | ((unsigned int)lb[7] << 16);
    *(uint4*)&Whi[(size_t)z * WN + i] = hv;
    *(uint4*)&Wlo[(size_t)z * WN + i] = lv;
}

// ---------------------------------------------------------------------------
// Projection via 3-term split-bf16 MFMA. Y = X @ W^T + bias.
// grid (M/128, 512/64, 3), 256 thr (4 waves), BM=128 BN=64 BK=64.
// ---------------------------------------------------------------------------
__global__ __launch_bounds__(256, 2) void proj_mfma(
    const float* __restrict__ X,
    const unsigned short* __restrict__ Whi, const unsigned short* __restrict__ Wlo,
    const float* __restrict__ bq, const float* __restrict__ bk, const float* __restrict__ bv,
    unsigned short* __restrict__ Qhi, unsigned short* __restrict__ Qlo,
    unsigned short* __restrict__ Khi, unsigned short* __restrict__ Klo,
    unsigned short* __restrict__ Vthi, unsigned short* __restrict__ Vtlo)
{
    const int z = blockIdx.z;
    const int m0 = blockIdx.x * 128;
    const int n0 = blockIdx.y * 64;
    const int tid = threadIdx.x;
    const int wid = tid >> 6, lane = tid & 63;
    const int lg = lane >> 4, lr = lane & 15;

    __shared__ __attribute__((aligned(16))) unsigned short smem[384 * 72];
    auto Xh  = (unsigned short(*)[72])(smem);
    auto Xl  = (unsigned short(*)[72])(smem + 128 * 72);
    auto Wh2 = (unsigned short(*)[72])(smem + 256 * 72);
    auto Wl2 = (unsigned short(*)[72])(smem + 320 * 72);

    const unsigned short* __restrict__ Wh = Whi + (size_t)z * WN;
    const unsigned short* __restrict__ Wl = Wlo + (size_t)z * WN;

    f32x4 acc[2][4];
    #pragma unroll
    for (int rt = 0; rt < 2; ++rt)
        #pragma unroll
        for (int nt = 0; nt < 4; ++nt) acc[rt][nt] = (f32x4){0.f, 0.f, 0.f, 0.f};

    const int xr = tid >> 1;
    const int xc = (tid & 1) * 32;

    for (int k0 = 0; k0 < DM; k0 += 64) {
        #pragma unroll
        for (int w = 0; w < 4; ++w) {
            float4 fa = *(const float4*)&X[(size_t)(m0 + xr) * DM + k0 + xc + w * 8];
            float4 fb = *(const float4*)&X[(size_t)(m0 + xr) * DM + k0 + xc + w * 8 + 4];
            float v[8] = {fa.x, fa.y, fa.z, fa.w, fb.x, fb.y, fb.z, fb.w};
            unsigned short hb[8], lb[8];
            #pragma unroll
            for (int k = 0; k < 8; ++k) splitbf(v[k], hb[k], lb[k]);
            uint4 hv, lv;
            hv.x = (unsigned int)hb[0] | ((unsigned int)hb[1] << 16);
            hv.y = (unsigned int)hb[2] | ((unsigned int)hb[3] << 16);
            hv.z = (unsigned int)hb[4] | ((unsigned int)hb[5] << 16);
            hv.w = (unsigned int)hb[6] | ((unsigned int)hb[7] << 16);
            lv.x = (unsigned int)lb[0] | ((unsigned int)lb[1] << 16);
            lv.y = (unsigned int)lb[2] | ((unsigned int)lb[3] << 16);
            lv.z = (unsigned int)lb[4] | ((unsigned int)lb[5] << 16);
            lv.w = (unsigned int)lb[6] | ((unsigned int)lb[7] << 16);
            *(uint4*)&Xh[xr][xc + w * 8] = hv;
            *(uint4*)&Xl[xr][xc + w * 8] = lv;
        }
        #pragma unroll
        for (int it = 0; it < 2; ++it) {
            int i2 = it * 256 + tid;
            int fr = i2 >> 3, ch = i2 & 7;
            *(int4*)&Wh2[fr][ch * 8] = *(const int4*)&Wh[(size_t)(n0 + fr) * DM + k0 + ch * 8];
            *(int4*)&Wl2[fr][ch * 8] = *(const int4*)&Wl[(size_t)(n0 + fr) * DM + k0 + ch * 8];
        }
        __syncthreads();

        __builtin_amdgcn_s_setprio(1);
        #pragma unroll
        for (int kc = 0; kc < 2; ++kc) {
            short8 xa[2][2];
            #pragma unroll
            for (int rt = 0; rt < 2; ++rt) {
                xa[rt][0] = __builtin_bit_cast(short8, *(const int4*)&Xh[wid * 32 + rt * 16 + lr][kc * 32 + lg * 8]);
                xa[rt][1] = __builtin_bit_cast(short8, *(const int4*)&Xl[wid * 32 + rt * 16 + lr][kc * 32 + lg * 8]);
            }
            #pragma unroll
            for (int nt = 0; nt < 4; ++nt) {
                short8 wh = __builtin_bit_cast(short8, *(const int4*)&Wh2[nt * 16 + lr][kc * 32 + lg * 8]);
                short8 wl = __builtin_bit_cast(short8, *(const int4*)&Wl2[nt * 16 + lr][kc * 32 + lg * 8]);
                #pragma unroll
                for (int rt = 0; rt < 2; ++rt) {
                    acc[rt][nt] = __builtin_amdgcn_mfma_f32_16x16x32_bf16(xa[rt][0], wh, acc[rt][nt], 0, 0, 0);
                    acc[rt][nt] = __builtin_amdgcn_mfma_f32_16x16x32_bf16(xa[rt][1], wh, acc[rt][nt], 0, 0, 0);
                    acc[rt][nt] = __builtin_amdgcn_mfma_f32_16x16x32_bf16(xa[rt][0], wl, acc[rt][nt], 0, 0, 0);
                }
            }
        }
        __builtin_amdgcn_s_setprio(0);
        __syncthreads();
    }

    if (z < 2) {
        const float* __restrict__ bias = (z == 0) ? bq : bk;
        unsigned short* __restrict__ Hi = (z == 0) ? Qhi : Khi;
        unsigned short* __restrict__ Lo = (z == 0) ? Qlo : Klo;
        const float sc = (z == 0) ? 0.125f : 1.0f;
        #pragma unroll
        for (int nt = 0; nt < 4; ++nt) {
            int n = n0 + nt * 16 + lr;
            float bv_ = bias[n];
            #pragma unroll
            for (int rt = 0; rt < 2; ++rt)
                #pragma unroll
                for (int r = 0; r < 4; ++r) {
                    int m = m0 + wid * 32 + rt * 16 + lg * 4 + r;
                    float y = (acc[rt][nt][r] + bv_) * sc;
                    unsigned short hb, lb;
                    splitbf(y, hb, lb);
                    Hi[(size_t)m * DM + n] = hb;
                    Lo[(size_t)m * DM + n] = lb;
                }
        }
    } else {
        unsigned int* Tk = (unsigned int*)smem;
        #pragma unroll
        for (int nt = 0; nt < 4; ++nt) {
            int d = nt * 16 + lr;
            float bv_ = bv[n0 + d];
            #pragma unroll
            for (int rt = 0; rt < 2; ++rt)
                #pragma unroll
                for (int r = 0; r < 4; ++r) {
                    int t = wid * 32 + rt * 16 + lg * 4 + r;
                    float y = acc[rt][nt][r] + bv_;
                    unsigned short hb, lb;
                    splitbf(y, hb, lb);
                    Tk[d * 132 + t] = (unsigned int)hb | ((unsigned int)lb << 16);
                }
        }
        __syncthreads();
        const int dl = tid >> 2, tq = tid & 3;
        const int bb = m0 >> 12, t0 = m0 & (TT - 1), h = n0 >> 6;
        size_t obase = ((size_t)((bb * NH + h) * HD + dl)) * TT + t0 + tq * 32;
        unsigned int hw[16], lw[16];
        #pragma unroll
        for (int k = 0; k < 16; ++k) {
            unsigned int u0 = Tk[dl * 132 + tq * 32 + 2 * k];
            unsigned int u1 = Tk[dl * 132 + tq * 32 + 2 * k + 1];
            hw[k] = (u0 & 0xFFFFu) | (u1 << 16);
            lw[k] = (u0 >> 16) | (u1 & 0xFFFF0000u);
        }
        #pragma unroll
        for (int j = 0; j < 4; ++j) {
            uint4 hv = {hw[4 * j], hw[4 * j + 1], hw[4 * j + 2], hw[4 * j + 3]};
            uint4 lv = {lw[4 * j], lw[4 * j + 1], lw[4 * j + 2], lw[4 * j + 3]};
            *(uint4*)&Vthi[obase + j * 8] = hv;
            *(uint4*)&Vtlo[obase + j * 8] = lv;
        }
    }
}

// ---------------------------------------------------------------------------
// Flash attention, operand-swapped, P-in-register. Staging via
// global_load_lds into LINEAR pitch-64 LDS with pre-swizzled global source
// (chunk ch -> slot ch^(row&7)); reads apply the same XOR. 64 krows/block,
// 4 waves, 32KB LDS -> 4 blocks/CU. XCD-aware flat-id remap: all 64 blocks
// of one (b,h) share an XCD (bh = flat & 15 -> flat%8 constant).
// ---------------------------------------------------------------------------
__global__ __launch_bounds__(256, 4) void attn_mfma(
    const unsigned short* __restrict__ Qhi, const unsigned short* __restrict__ Qlo,
    const unsigned short* __restrict__ Khi, const unsigned short* __restrict__ Klo,
    const unsigned short* __restrict__ Vthi, const unsigned short* __restrict__ Vtlo,
    float* __restrict__ Out)
{
    const int flat = blockIdx.x + 64 * (blockIdx.y + 8 * blockIdx.z);
    const int bh = flat & 15;
    const int r0 = (flat >> 4) * 64;
    const int b = bh >> 3, h = bh & 7;
    const int tid = threadIdx.x;
    const int wid = tid >> 6, lane = tid & 63;
    const int lg = lane >> 4, lr = lane & 15;
    const int wr0 = r0 + wid * 16;

    // linear pitch-64 (128B rows), swizzled content: chunk ch of row R sits at
    // slot ch^(R&7). Total 32KB -> 4 blocks/CU.
    __shared__ __attribute__((aligned(16))) unsigned short Qs[128][64]; // hi 0-63 (perm q), lo 64-127
    __shared__ __attribute__((aligned(16))) unsigned short Vs[128][64]; // V^T rows d: hi 0-63, lo 64-127

    const size_t qbase = (size_t)b * TT * DM + h * HD;
    const size_t vbase = ((size_t)(b * NH + h)) * HD * TT;

    // K fragments (B-operand: col=krow=lr, k=d) resident in registers
    short8 kf[2][2];
    #pragma unroll
    for (int kc = 0; kc < 2; ++kc) {
        size_t g = qbase + (size_t)(wr0 + lr) * DM + kc * 32 + lg * 8;
        kf[kc][0] = __builtin_bit_cast(short8, *(const int4*)&Khi[g]);
        kf[kc][1] = __builtin_bit_cast(short8, *(const int4*)&Klo[g]);
    }

    float m_s = -INFINITY, l_s = 0.f;
    f32x4 oacc[4];
    #pragma unroll
    for (int dt = 0; dt < 4; ++dt) oacc[dt] = (f32x4){0.f, 0.f, 0.f, 0.f};

    for (int c0 = 0; c0 < TT; c0 += 64) {
        // ---- stage Q/V via global_load_lds (pre-swizzled source, linear dest)
        #pragma unroll
        for (int it = 0; it < 4; ++it) {
            int gi = it * 256 + tid;
            int fr = gi >> 3;
            int ch = (gi & 7) ^ (fr & 7);           // inverse swizzle on source
            int ldsoff = (it * 256 + wid * 64) * 16; // wave-uniform dest base
            const unsigned short* qsrc = (fr < 64) ? Qhi : Qlo;
            GLD16(&qsrc[qbase + (size_t)(c0 + qperm(fr & 63)) * DM + ch * 8],
                  (char*)&Qs[0][0] + ldsoff);
            const unsigned short* vsrc = (fr < 64) ? Vthi : Vtlo;
            GLD16(&vsrc[vbase + (size_t)(fr & 63) * TT + c0 + ch * 8],
                  (char*)&Vs[0][0] + ldsoff);
        }
        __syncthreads();   // drains vmcnt -> staged data visible

        // S^T = Q @ K^T (3-term split): sacc[qt] row=q~tile-row, col=krow
        f32x4 sacc[4];
        #pragma unroll
        for (int qt = 0; qt < 4; ++qt) sacc[qt] = (f32x4){0.f, 0.f, 0.f, 0.f};
        __builtin_amdgcn_s_setprio(1);
        #pragma unroll
        for (int kc = 0; kc < 2; ++kc) {
            #pragma unroll
            for (int qt = 0; qt < 4; ++qt) {
                int row = qt * 16 + lr;
                int ch = kc * 4 + lg;
                int so = (ch ^ (row & 7)) * 16;
                short8 qh = __builtin_bit_cast(short8,
                    *(const int4*)((const char*)&Qs[row][0] + so));
                short8 ql = __builtin_bit_cast(short8,
                    *(const int4*)((const char*)&Qs[64 + row][0] + so));
                sacc[qt] = __builtin_amdgcn_mfma_f32_16x16x32_bf16(qh, kf[kc][0], sacc[qt], 0, 0, 0);
                sacc[qt] = __builtin_amdgcn_mfma_f32_16x16x32_bf16(ql, kf[kc][0], sacc[qt], 0, 0, 0);
                sacc[qt] = __builtin_amdgcn_mfma_f32_16x16x32_bf16(qh, kf[kc][1], sacc[qt], 0, 0, 0);
            }
        }
        __builtin_amdgcn_s_setprio(0);

        // online softmax (per-lane: krow = wr0+lr) + pack P hi/lo in-register
        unsigned int hp[4][2], lp[4][2];
        {
            float mx = -INFINITY;
            #pragma unroll
            for (int qt = 0; qt < 4; ++qt)
                #pragma unroll
                for (int r = 0; r < 4; ++r) mx = fmaxf(mx, sacc[qt][r]);
            mx = fmaxf(mx, __shfl_xor(mx, 16));
            mx = fmaxf(mx, __shfl_xor(mx, 32));
            float nm = fmaxf(m_s, mx);
            float al = __expf(m_s - nm);
            float sum = 0.f;
            #pragma unroll
            for (int qt = 0; qt < 4; ++qt)
                #pragma unroll
                for (int r = 0; r < 4; ++r) {
                    float p = __expf(sacc[qt][r] - nm);
                    sacc[qt][r] = p;
                    sum += p;
                }
            sum += __shfl_xor(sum, 16);
            sum += __shfl_xor(sum, 32);
            m_s = nm;
            l_s = l_s * al + sum;
            // pack: r-pairs -> u32 of 2 bf16 (these ARE the PV B-frag words)
            #pragma unroll
            for (int qt = 0; qt < 4; ++qt)
                #pragma unroll
                for (int pp = 0; pp < 2; ++pp) {
                    float p0 = sacc[qt][2 * pp];
                    float p1 = sacc[qt][2 * pp + 1];
                    unsigned int u0 = __builtin_bit_cast(unsigned int, p0);
                    unsigned int u1 = __builtin_bit_cast(unsigned int, p1);
                    unsigned int h0 = u0 >> 16, h1 = u1 & 0xFFFF0000u;
                    hp[qt][pp] = h0 | h1;
                    float r0f = p0 - bf2f((unsigned short)h0);
                    float r1f = p1 - bf2f((unsigned short)(u1 >> 16));
                    lp[qt][pp] = (__builtin_bit_cast(unsigned int, r0f) >> 16)
                               | (__builtin_bit_cast(unsigned int, r1f) & 0xFFFF0000u);
                }
            // rescale accumulated output
            #pragma unroll
            for (int dt = 0; dt < 4; ++dt)
                #pragma unroll
                for (int r = 0; r < 4; ++r) oacc[dt][r] *= al;
        }

        // out^T += V^T @ P (3-term split)
        __builtin_amdgcn_s_setprio(1);
        #pragma unroll
        for (int c = 0; c < 2; ++c) {
            int4 ph4 = {(int)hp[2 * c][0], (int)hp[2 * c][1],
                        (int)hp[2 * c + 1][0], (int)hp[2 * c + 1][1]};
            int4 pl4 = {(int)lp[2 * c][0], (int)lp[2 * c][1],
                        (int)lp[2 * c + 1][0], (int)lp[2 * c + 1][1]};
            short8 pf  = __builtin_bit_cast(short8, ph4);
            short8 plf = __builtin_bit_cast(short8, pl4);
            #pragma unroll
            for (int dt = 0; dt < 4; ++dt) {
                int row = dt * 16 + lr;
                int ch = c * 4 + lg;
                int so = (ch ^ (row & 7)) * 16;
                short8 vh = __builtin_bit_cast(short8,
                    *(const int4*)((const char*)&Vs[row][0] + so));
                short8 vl = __builtin_bit_cast(short8,
                    *(const int4*)((const char*)&Vs[64 + row][0] + so));
                oacc[dt] = __builtin_amdgcn_mfma_f32_16x16x32_bf16(vh, pf,  oacc[dt], 0, 0, 0);
                oacc[dt] = __builtin_amdgcn_mfma_f32_16x16x32_bf16(vl, pf,  oacc[dt], 0, 0, 0);
                oacc[dt] = __builtin_amdgcn_mfma_f32_16x16x32_bf16(vh, plf, oacc[dt], 0, 0, 0);
            }
        }
        __builtin_amdgcn_s_setprio(0);
        __syncthreads();   // all waves done reading Qs/Vs before next stage
    }

    // epilogue: out[krow][d] = oacc / l  (all lane-local)
    {
        float inv = __builtin_amdgcn_rcpf(l_s);
        int row = wr0 + lr;
        #pragma unroll
        for (int dt = 0; dt < 4; ++dt)
            #pragma unroll
            for (int r = 0; r < 4; ++r)
                Out[((size_t)(b * TT + row)) * DM + h * HD + dt * 16 + lg * 4 + r] =
                    oacc[dt][r] * inv;
    }
}

// ---------------------------------------------------------------------------
extern "C" void kernel_launch(void* const* d_in, const int* in_sizes, int n_in,
                              void* d_out, int out_size, void* d_ws, size_t ws_size,
                              hipStream_t stream)
{
    const float* x  = (const float*)d_in[0];
    const float* Wk = (const float*)d_in[1];
    const float* bk = (const float*)d_in[2];
    const float* Wq = (const float*)d_in[3];
    const float* bq = (const float*)d_in[4];
    const float* Wv = (const float*)d_in[5];
    const float* bv = (const float*)d_in[6];
    float* out = (float*)d_out;

    const size_t SZ = (size_t)2 * TT * DM;
    unsigned short* Qhi  = (unsigned short*)d_ws;
    unsigned short* Qlo  = Qhi + SZ;
    unsigned short* Khi  = Qlo + SZ;
    unsigned short* Klo  = Khi + SZ;
    unsigned short* Vthi = Klo + SZ;
    unsigned short* Vtlo = Vthi + SZ;
    unsigned short* Whi  = Vtlo + SZ;
    unsigned short* Wlo  = Whi + (size_t)3 * WN;

    wsplit<<<dim3(WN / 2048, 3), dim3(256), 0, stream>>>(Wq, Wk, Wv, Whi, Wlo);

    dim3 pgrid(2 * TT / 128, DM / 64, 3);
    proj_mfma<<<pgrid, dim3(256), 0, stream>>>(x, Whi, Wlo, bq, bk, bv,
                                               Qhi, Qlo, Khi, Klo, Vthi, Vtlo);

    dim3 agrid(TT / 64, NH, 2);
    attn_mfma<<<agrid, dim3(256), 0, stream>>>(Qhi, Qlo, Khi, Klo, Vthi, Vtlo, out);
}

// Round 7
// 221.417 us; speedup vs baseline: 2.9340x; 1.3004x over previous
//
#include <hip/hip_runtime.h>
#include <math.h>

#define TT 4096
#define DM 512
#define NH 8
#define HD 64
#define WN (DM * DM)   // 262144 elements per weight matrix

typedef float f32x4 __attribute__((ext_vector_type(4)));
typedef short short8 __attribute__((ext_vector_type(8)));
typedef _Float16 half8 __attribute__((ext_vector_type(8)));

#define GLD16(gp, lp) __builtin_amdgcn_global_load_lds( \
    (const __attribute__((address_space(1))) void*)(gp), \
    (__attribute__((address_space(3))) void*)(lp), 16, 0, 0)

static __device__ __forceinline__ float bf2f(unsigned short h) {
    unsigned int u = ((unsigned int)h) << 16;
    return __builtin_bit_cast(float, u);
}
// bf16 truncation split (for proj X/W staging)
static __device__ __forceinline__ void splitbf(float x, unsigned short& hi, unsigned short& lo) {
    unsigned int u = __builtin_bit_cast(unsigned int, x);
    hi = (unsigned short)(u >> 16);
    float r = x - bf2f(hi);
    lo = (unsigned short)(__builtin_bit_cast(unsigned int, r) >> 16);
}
// fp16 RTN split (for Q/K outputs): x = hi + lo to ~2^-22 rel
static __device__ __forceinline__ void splitf16(float x, unsigned short& hi, unsigned short& lo) {
    _Float16 h = (_Float16)x;
    hi = __builtin_bit_cast(unsigned short, h);
    _Float16 l = (_Float16)(x - (float)h);
    lo = __builtin_bit_cast(unsigned short, l);
}
// Q-row permutation: LDS row rho holds global q-row qperm(rho). Maps MFMA C-rows
// (lg*4+r) onto PV B-frag k-slots (lg*8+j) so P stays in registers.
static __device__ __forceinline__ int qperm(int r) {
    return ((r >> 5) << 5) | (((r >> 2) & 3) << 3) | (((r >> 4) & 1) << 2) | (r & 3);
}

// ---------------------------------------------------------------------------
// Pre-split the three weight matrices into bf16 hi/lo. grid (128, 3), 256 thr.
// ---------------------------------------------------------------------------
__global__ __launch_bounds__(256) void wsplit(
    const float* __restrict__ Wq, const float* __restrict__ Wk, const float* __restrict__ Wv,
    unsigned short* __restrict__ Whi, unsigned short* __restrict__ Wlo)
{
    const int z = blockIdx.y;
    const float* __restrict__ src = (z == 0) ? Wq : (z == 1) ? Wk : Wv;
    const int i = (blockIdx.x * 256 + threadIdx.x) * 8;
    float4 a = *(const float4*)&src[i];
    float4 b = *(const float4*)&src[i + 4];
    float v[8] = {a.x, a.y, a.z, a.w, b.x, b.y, b.z, b.w};
    unsigned short hb[8], lb[8];
    #pragma unroll
    for (int k = 0; k < 8; ++k) splitbf(v[k], hb[k], lb[k]);
    uint4 hv, lv;
    hv.x = (unsigned int)hb[0] | ((unsigned int)hb[1] << 16);
    hv.y = (unsigned int)hb[2] | ((unsigned int)hb[3] << 16);
    hv.z = (unsigned int)hb[4] | ((unsigned int)hb[5] << 16);
    hv.w = (unsigned int)hb[6] | ((unsigned int)hb[7] << 16);
    lv.x = (unsigned int)lb[0] | ((unsigned int)lb[1] << 16);
    lv.y = (unsigned int)lb[2] | ((unsigned int)lb[3] << 16);
    lv.z = (unsigned int)lb[4] | ((unsigned int)lb[5] << 16);
    lv.w = (unsigned int)lb[6] | ((unsigned int)lb[7] << 16);
    *(uint4*)&Whi[(size_t)z * WN + i] = hv;
    *(uint4*)&Wlo[(size_t)z * WN + i] = lv;
}

// ---------------------------------------------------------------------------
// Projection via 3-term split-bf16 MFMA. Y = X @ W^T + bias.
// grid (M/128, 512/64, 3), 256 thr (4 waves), BM=128 BN=64 BK=64.
//   z=0: Q -> fp16 (Qhi,Qlo), pre-scaled 0.125
//   z=1: K -> fp16 (Khi,Klo)
//   z=2: V -> single fp16, transposed [b][h][d][T]
// ---------------------------------------------------------------------------
__global__ __launch_bounds__(256, 2) void proj_mfma(
    const float* __restrict__ X,
    const unsigned short* __restrict__ Whi, const unsigned short* __restrict__ Wlo,
    const float* __restrict__ bq, const float* __restrict__ bk, const float* __restrict__ bv,
    unsigned short* __restrict__ Qhi, unsigned short* __restrict__ Qlo,
    unsigned short* __restrict__ Khi, unsigned short* __restrict__ Klo,
    unsigned short* __restrict__ Vt)
{
    const int z = blockIdx.z;
    const int m0 = blockIdx.x * 128;
    const int n0 = blockIdx.y * 64;
    const int tid = threadIdx.x;
    const int wid = tid >> 6, lane = tid & 63;
    const int lg = lane >> 4, lr = lane & 15;

    __shared__ __attribute__((aligned(16))) unsigned short smem[384 * 72];
    auto Xh  = (unsigned short(*)[72])(smem);
    auto Xl  = (unsigned short(*)[72])(smem + 128 * 72);
    auto Wh2 = (unsigned short(*)[72])(smem + 256 * 72);
    auto Wl2 = (unsigned short(*)[72])(smem + 320 * 72);

    const unsigned short* __restrict__ Wh = Whi + (size_t)z * WN;
    const unsigned short* __restrict__ Wl = Wlo + (size_t)z * WN;

    f32x4 acc[2][4];
    #pragma unroll
    for (int rt = 0; rt < 2; ++rt)
        #pragma unroll
        for (int nt = 0; nt < 4; ++nt) acc[rt][nt] = (f32x4){0.f, 0.f, 0.f, 0.f};

    const int xr = tid >> 1;
    const int xc = (tid & 1) * 32;

    for (int k0 = 0; k0 < DM; k0 += 64) {
        #pragma unroll
        for (int w = 0; w < 4; ++w) {
            float4 fa = *(const float4*)&X[(size_t)(m0 + xr) * DM + k0 + xc + w * 8];
            float4 fb = *(const float4*)&X[(size_t)(m0 + xr) * DM + k0 + xc + w * 8 + 4];
            float v[8] = {fa.x, fa.y, fa.z, fa.w, fb.x, fb.y, fb.z, fb.w};
            unsigned short hb[8], lb[8];
            #pragma unroll
            for (int k = 0; k < 8; ++k) splitbf(v[k], hb[k], lb[k]);
            uint4 hv, lv;
            hv.x = (unsigned int)hb[0] | ((unsigned int)hb[1] << 16);
            hv.y = (unsigned int)hb[2] | ((unsigned int)hb[3] << 16);
            hv.z = (unsigned int)hb[4] | ((unsigned int)hb[5] << 16);
            hv.w = (unsigned int)hb[6] | ((unsigned int)hb[7] << 16);
            lv.x = (unsigned int)lb[0] | ((unsigned int)lb[1] << 16);
            lv.y = (unsigned int)lb[2] | ((unsigned int)lb[3] << 16);
            lv.z = (unsigned int)lb[4] | ((unsigned int)lb[5] << 16);
            lv.w = (unsigned int)lb[6] | ((unsigned int)lb[7] << 16);
            *(uint4*)&Xh[xr][xc + w * 8] = hv;
            *(uint4*)&Xl[xr][xc + w * 8] = lv;
        }
        #pragma unroll
        for (int it = 0; it < 2; ++it) {
            int i2 = it * 256 + tid;
            int fr = i2 >> 3, ch = i2 & 7;
            *(int4*)&Wh2[fr][ch * 8] = *(const int4*)&Wh[(size_t)(n0 + fr) * DM + k0 + ch * 8];
            *(int4*)&Wl2[fr][ch * 8] = *(const int4*)&Wl[(size_t)(n0 + fr) * DM + k0 + ch * 8];
        }
        __syncthreads();

        __builtin_amdgcn_s_setprio(1);
        #pragma unroll
        for (int kc = 0; kc < 2; ++kc) {
            short8 xa[2][2];
            #pragma unroll
            for (int rt = 0; rt < 2; ++rt) {
                xa[rt][0] = __builtin_bit_cast(short8, *(const int4*)&Xh[wid * 32 + rt * 16 + lr][kc * 32 + lg * 8]);
                xa[rt][1] = __builtin_bit_cast(short8, *(const int4*)&Xl[wid * 32 + rt * 16 + lr][kc * 32 + lg * 8]);
            }
            #pragma unroll
            for (int nt = 0; nt < 4; ++nt) {
                short8 wh = __builtin_bit_cast(short8, *(const int4*)&Wh2[nt * 16 + lr][kc * 32 + lg * 8]);
                short8 wl = __builtin_bit_cast(short8, *(const int4*)&Wl2[nt * 16 + lr][kc * 32 + lg * 8]);
                #pragma unroll
                for (int rt = 0; rt < 2; ++rt) {
                    acc[rt][nt] = __builtin_amdgcn_mfma_f32_16x16x32_bf16(xa[rt][0], wh, acc[rt][nt], 0, 0, 0);
                    acc[rt][nt] = __builtin_amdgcn_mfma_f32_16x16x32_bf16(xa[rt][1], wh, acc[rt][nt], 0, 0, 0);
                    acc[rt][nt] = __builtin_amdgcn_mfma_f32_16x16x32_bf16(xa[rt][0], wl, acc[rt][nt], 0, 0, 0);
                }
            }
        }
        __builtin_amdgcn_s_setprio(0);
        __syncthreads();
    }

    if (z < 2) {
        const float* __restrict__ bias = (z == 0) ? bq : bk;
        unsigned short* __restrict__ Hi = (z == 0) ? Qhi : Khi;
        unsigned short* __restrict__ Lo = (z == 0) ? Qlo : Klo;
        const float sc = (z == 0) ? 0.125f : 1.0f;
        #pragma unroll
        for (int nt = 0; nt < 4; ++nt) {
            int n = n0 + nt * 16 + lr;
            float bv_ = bias[n];
            #pragma unroll
            for (int rt = 0; rt < 2; ++rt)
                #pragma unroll
                for (int r = 0; r < 4; ++r) {
                    int m = m0 + wid * 32 + rt * 16 + lg * 4 + r;
                    float y = (acc[rt][nt][r] + bv_) * sc;
                    unsigned short hb, lb;
                    splitf16(y, hb, lb);
                    Hi[(size_t)m * DM + n] = hb;
                    Lo[(size_t)m * DM + n] = lb;
                }
        }
    } else {
        // V: single fp16, bounce through LDS, write transposed [b][h][d][T]
        unsigned short* Tk = (unsigned short*)smem;   // [64][136]
        #pragma unroll
        for (int nt = 0; nt < 4; ++nt) {
            int d = nt * 16 + lr;
            float bv_ = bv[n0 + d];
            #pragma unroll
            for (int rt = 0; rt < 2; ++rt)
                #pragma unroll
                for (int r = 0; r < 4; ++r) {
                    int t = wid * 32 + rt * 16 + lg * 4 + r;
                    float y = acc[rt][nt][r] + bv_;
                    Tk[d * 136 + t] = __builtin_bit_cast(unsigned short, (_Float16)y);
                }
        }
        __syncthreads();
        const int dl = tid >> 2, tq = tid & 3;
        const int bb = m0 >> 12, t0 = m0 & (TT - 1), h = n0 >> 6;
        size_t obase = ((size_t)((bb * NH + h) * HD + dl)) * TT + t0 + tq * 32;
        unsigned int w[16];
        #pragma unroll
        for (int k = 0; k < 16; ++k)
            w[k] = (unsigned int)Tk[dl * 136 + tq * 32 + 2 * k]
                 | ((unsigned int)Tk[dl * 136 + tq * 32 + 2 * k + 1] << 16);
        #pragma unroll
        for (int j = 0; j < 4; ++j) {
            uint4 wv = {w[4 * j], w[4 * j + 1], w[4 * j + 2], w[4 * j + 3]};
            *(uint4*)&Vt[obase + j * 8] = wv;
        }
    }
}

// ---------------------------------------------------------------------------
// Flash attention, fp16 path. S = K@Q^T via 3-term fp16 split (operand-swapped
// S^T = mfma(Q,K)); PV single-term fp16 with P scaled by e^7.6246 (=2048) to
// dodge fp16 subnormals; scale cancels in oacc/l. 32 krows/wave, 128/block.
// Staging: global_load_lds, linear LDS, pre-swizzled source. grid 512 (1-D).
// ---------------------------------------------------------------------------
__global__ __launch_bounds__(256, 3) void attn_mfma(
    const unsigned short* __restrict__ Qhi, const unsigned short* __restrict__ Qlo,
    const unsigned short* __restrict__ Khi, const unsigned short* __restrict__ Klo,
    const unsigned short* __restrict__ Vt,
    float* __restrict__ Out)
{
    const int flat = blockIdx.x;
    const int bh = flat & 15;                 // XCD-grouping: same bh -> same XCD
    const int r0 = (flat >> 4) * 128;
    const int b = bh >> 3, h = bh & 7;
    const int tid = threadIdx.x;
    const int wid = tid >> 6, lane = tid & 63;
    const int lg = lane >> 4, lr = lane & 15;
    const int wr0 = r0 + wid * 32;

    __shared__ __attribute__((aligned(16))) unsigned short Qs[128][64]; // perm q rows: hi 0-63, lo 64-127
    __shared__ __attribute__((aligned(16))) unsigned short Vs[64][64];  // V^T rows d (single fp16)

    const size_t qbase = (size_t)b * TT * DM + h * HD;
    const size_t vbase = ((size_t)(b * NH + h)) * HD * TT;

    // K fragments resident in registers: [rowtile][kc][hi/lo]
    half8 kf[2][2][2];
    #pragma unroll
    for (int rt = 0; rt < 2; ++rt)
        #pragma unroll
        for (int kc = 0; kc < 2; ++kc) {
            size_t g = qbase + (size_t)(wr0 + rt * 16 + lr) * DM + kc * 32 + lg * 8;
            kf[rt][kc][0] = __builtin_bit_cast(half8, *(const int4*)&Khi[g]);
            kf[rt][kc][1] = __builtin_bit_cast(half8, *(const int4*)&Klo[g]);
        }

    float m_s[2], l_s[2];
    f32x4 oacc[2][4];
    #pragma unroll
    for (int rt = 0; rt < 2; ++rt) {
        m_s[rt] = -INFINITY; l_s[rt] = 0.f;
        #pragma unroll
        for (int dt = 0; dt < 4; ++dt) oacc[rt][dt] = (f32x4){0.f, 0.f, 0.f, 0.f};
    }

    for (int c0 = 0; c0 < TT; c0 += 64) {
        // ---- stage Q hi/lo (4x) and V (2x) via global_load_lds, swizzled src
        #pragma unroll
        for (int it = 0; it < 4; ++it) {
            int gi = it * 256 + tid;
            int fr = gi >> 3;
            int ch = (gi & 7) ^ (fr & 7);
            const unsigned short* qsrc = (fr < 64) ? Qhi : Qlo;
            GLD16(&qsrc[qbase + (size_t)(c0 + qperm(fr & 63)) * DM + ch * 8],
                  (char*)&Qs[0][0] + (it * 256 + wid * 64) * 16);
        }
        #pragma unroll
        for (int it = 0; it < 2; ++it) {
            int gi = it * 256 + tid;
            int fr = gi >> 3;
            int ch = (gi & 7) ^ (fr & 7);
            GLD16(&Vt[vbase + (size_t)fr * TT + c0 + ch * 8],
                  (char*)&Vs[0][0] + (it * 256 + wid * 64) * 16);
        }
        __syncthreads();

        // ---- S^T = Q @ K^T, 3-term fp16 split
        f32x4 sacc[2][4];
        #pragma unroll
        for (int rt = 0; rt < 2; ++rt)
            #pragma unroll
            for (int qt = 0; qt < 4; ++qt) sacc[rt][qt] = (f32x4){0.f, 0.f, 0.f, 0.f};
        __builtin_amdgcn_s_setprio(1);
        #pragma unroll
        for (int kc = 0; kc < 2; ++kc) {
            #pragma unroll
            for (int qt = 0; qt < 4; ++qt) {
                int row = qt * 16 + lr;
                int so = ((kc * 4 + lg) ^ (row & 7)) * 16;
                half8 qh = __builtin_bit_cast(half8, *(const int4*)((const char*)&Qs[row][0] + so));
                half8 ql = __builtin_bit_cast(half8, *(const int4*)((const char*)&Qs[64 + row][0] + so));
                #pragma unroll
                for (int rt = 0; rt < 2; ++rt) {
                    sacc[rt][qt] = __builtin_amdgcn_mfma_f32_16x16x32_f16(qh, kf[rt][kc][0], sacc[rt][qt], 0, 0, 0);
                    sacc[rt][qt] = __builtin_amdgcn_mfma_f32_16x16x32_f16(ql, kf[rt][kc][0], sacc[rt][qt], 0, 0, 0);
                    sacc[rt][qt] = __builtin_amdgcn_mfma_f32_16x16x32_f16(qh, kf[rt][kc][1], sacc[rt][qt], 0, 0, 0);
                }
            }
        }
        __builtin_amdgcn_s_setprio(0);

        // ---- online softmax per krow (lane-local col) + fp16 pack, scaled e^7.62
        unsigned int hp[2][4][2];
        #pragma unroll
        for (int rt = 0; rt < 2; ++rt) {
            float mx = -INFINITY;
            #pragma unroll
            for (int qt = 0; qt < 4; ++qt)
                #pragma unroll
                for (int r = 0; r < 4; ++r) mx = fmaxf(mx, sacc[rt][qt][r]);
            mx = fmaxf(mx, __shfl_xor(mx, 16));
            mx = fmaxf(mx, __shfl_xor(mx, 32));
            float nm = fmaxf(m_s[rt], mx);
            float al = __expf(m_s[rt] - nm);
            const float nmb = nm - 7.6246190f;       // ln(2048): p' = 2048*p
            float sum = 0.f;
            #pragma unroll
            for (int qt = 0; qt < 4; ++qt)
                #pragma unroll
                for (int r = 0; r < 4; ++r) {
                    float p = __expf(sacc[rt][qt][r] - nmb);
                    sacc[rt][qt][r] = p;
                    sum += p;
                }
            sum += __shfl_xor(sum, 16);
            sum += __shfl_xor(sum, 32);
            m_s[rt] = nm;
            l_s[rt] = l_s[rt] * al + sum;
            #pragma unroll
            for (int qt = 0; qt < 4; ++qt)
                #pragma unroll
                for (int pp = 0; pp < 2; ++pp)
                    hp[rt][qt][pp] = __builtin_bit_cast(unsigned int,
                        __builtin_amdgcn_cvt_pkrtz(sacc[rt][qt][2 * pp], sacc[rt][qt][2 * pp + 1]));
            #pragma unroll
            for (int dt = 0; dt < 4; ++dt)
                #pragma unroll
                for (int r = 0; r < 4; ++r) oacc[rt][dt][r] *= al;
        }

        // ---- out^T += V^T @ P, single fp16 term
        __builtin_amdgcn_s_setprio(1);
        #pragma unroll
        for (int c = 0; c < 2; ++c) {
            half8 pf[2];
            #pragma unroll
            for (int rt = 0; rt < 2; ++rt) {
                int4 ph4 = {(int)hp[rt][2 * c][0], (int)hp[rt][2 * c][1],
                            (int)hp[rt][2 * c + 1][0], (int)hp[rt][2 * c + 1][1]};
                pf[rt] = __builtin_bit_cast(half8, ph4);
            }
            #pragma unroll
            for (int dt = 0; dt < 4; ++dt) {
                int row = dt * 16 + lr;
                int so = ((c * 4 + lg) ^ (row & 7)) * 16;
                half8 vh = __builtin_bit_cast(half8, *(const int4*)((const char*)&Vs[row][0] + so));
                #pragma unroll
                for (int rt = 0; rt < 2; ++rt)
                    oacc[rt][dt] = __builtin_amdgcn_mfma_f32_16x16x32_f16(vh, pf[rt], oacc[rt][dt], 0, 0, 0);
            }
        }
        __builtin_amdgcn_s_setprio(0);
        __syncthreads();
    }

    // epilogue: out[krow][d] = oacc / l  (scale 2048 cancels)
    #pragma unroll
    for (int rt = 0; rt < 2; ++rt) {
        float inv = __builtin_amdgcn_rcpf(l_s[rt]);
        int row = wr0 + rt * 16 + lr;
        #pragma unroll
        for (int dt = 0; dt < 4; ++dt)
            #pragma unroll
            for (int r = 0; r < 4; ++r)
                Out[((size_t)(b * TT + row)) * DM + h * HD + dt * 16 + lg * 4 + r] =
                    oacc[rt][dt][r] * inv;
    }
}

// ---------------------------------------------------------------------------
extern "C" void kernel_launch(void* const* d_in, const int* in_sizes, int n_in,
                              void* d_out, int out_size, void* d_ws, size_t ws_size,
                              hipStream_t stream)
{
    const float* x  = (const float*)d_in[0];
    const float* Wk = (const float*)d_in[1];
    const float* bk = (const float*)d_in[2];
    const float* Wq = (const float*)d_in[3];
    const float* bq = (const float*)d_in[4];
    const float* Wv = (const float*)d_in[5];
    const float* bv = (const float*)d_in[6];
    float* out = (float*)d_out;

    const size_t SZ = (size_t)2 * TT * DM;
    unsigned short* Qhi = (unsigned short*)d_ws;
    unsigned short* Qlo = Qhi + SZ;
    unsigned short* Khi = Qlo + SZ;
    unsigned short* Klo = Khi + SZ;
    unsigned short* Vt  = Klo + SZ;
    unsigned short* Whi = Vt + SZ;
    unsigned short* Wlo = Whi + (size_t)3 * WN;

    wsplit<<<dim3(WN / 2048, 3), dim3(256), 0, stream>>>(Wq, Wk, Wv, Whi, Wlo);

    dim3 pgrid(2 * TT / 128, DM / 64, 3);
    proj_mfma<<<pgrid, dim3(256), 0, stream>>>(x, Whi, Wlo, bq, bk, bv,
                                               Qhi, Qlo, Khi, Klo, Vt);

    attn_mfma<<<dim3(512), dim3(256), 0, stream>>>(Qhi, Qlo, Khi, Klo, Vt, out);
}